// Round 4
// baseline (427.782 us; speedup 1.0000x reference)
//
#include <hip/hip_runtime.h>

#define TPB 512
#define QPT 8    // preds per thread
#define NSEG 64  // gt-dimension split

// Order-preserving float<->uint encoding so atomicMin(uint) == float min.
__device__ __forceinline__ unsigned encf(float f) {
    unsigned u = __float_as_uint(f);
    return (u & 0x80000000u) ? ~u : (u | 0x80000000u);
}
__device__ __forceinline__ float decf(unsigned u) {
    return __uint_as_float((u & 0x80000000u) ? (u ^ 0x80000000u) : ~u);
}

// preds packed as {-2x, -2y, -2z, ||p||^2}; gts packed as {x, y, z, ||g||^2}.
__global__ void __launch_bounds__(256) pack_preds(const float* __restrict__ pts,
                                                  float4* __restrict__ out, int total) {
    int i = blockIdx.x * blockDim.x + threadIdx.x;
    if (i < total) {
        float x = pts[3 * i], y = pts[3 * i + 1], z = pts[3 * i + 2];
        out[i] = make_float4(-2.f * x, -2.f * y, -2.f * z, fmaf(x, x, fmaf(y, y, z * z)));
    }
}
__global__ void __launch_bounds__(256) pack_gts(const float* __restrict__ pts,
                                                float4* __restrict__ out, int total) {
    int i = blockIdx.x * blockDim.x + threadIdx.x;
    if (i < total) {
        float x = pts[3 * i], y = pts[3 * i + 1], z = pts[3 * i + 2];
        out[i] = make_float4(x, y, z, fmaf(x, x, fmaf(y, y, z * z)));
    }
}
__global__ void __launch_bounds__(256) init_mins(unsigned* __restrict__ u, int total) {
    int i = blockIdx.x * blockDim.x + threadIdx.x;
    if (i < total) u[i] = 0xFFFFFFFFu;  // encodes +max — identity for min
}

// min over j of (d[j] + pw[j]), then min over each 16-lane group (4 butterfly
// stages; shuffles issue on the LDS pipe, off the VALU critical resource).
__device__ __forceinline__ float gt_reduce(const float* d, const float* pw) {
    float e0 = d[0] + pw[0], e1 = d[1] + pw[1], e2 = d[2] + pw[2], e3 = d[3] + pw[3];
    float e4 = d[4] + pw[4], e5 = d[5] + pw[5], e6 = d[6] + pw[6], e7 = d[7] + pw[7];
    float a = fminf(fminf(e0, e1), e2);   // -> v_min3_f32
    float b = fminf(fminf(e3, e4), e5);
    float c = fminf(fminf(a, b), e6);
    float t = fminf(c, e7);
    t = fminf(t, __shfl_xor(t, 1));
    t = fminf(t, __shfl_xor(t, 2));
    t = fminf(t, __shfl_xor(t, 4));
    t = fminf(t, __shfl_xor(t, 8));
    return t;  // lanes 0,16,32,48 each hold their 16-lane-group min
}

// Fused single pass over all (pred, gt) pairs. Grid: (predChunks, NSEG, B).
// d = ||g||^2 - 2 p.g computed ONCE per pair feeds:
//   pred-side: register min over gts (+||p||^2 folded at the end), and
//   gt-side:   (d + ||p||^2) reduced over 8 j's and 64 lanes -> atomicMin.
__global__ void __launch_bounds__(TPB, 8) fused_chamfer(const float4* __restrict__ P4,
                                                        const float4* __restrict__ G4,
                                                        unsigned* __restrict__ upred,
                                                        unsigned* __restrict__ ugt,
                                                        int N, int M, int B) {
    const int b     = blockIdx.z;
    const int seg   = blockIdx.y;
    const int chunk = blockIdx.x;

    const float4* __restrict__ Q = P4 + (size_t)b * N;
    const float4* __restrict__ R = G4 + (size_t)b * M;

    const int segLen = (M + NSEG - 1) / NSEG;
    const int s0 = seg * segLen;
    const int s1 = (s0 + segLen < M) ? (s0 + segLen) : M;
    if (s0 >= s1) return;

    const int lane  = (int)threadIdx.x & 63;
    const int qbase = chunk * (TPB * QPT) + (int)threadIdx.x;

    float p2x[QPT], p2y[QPT], p2z[QPT], pw[QPT], m[QPT];
    #pragma unroll
    for (int j = 0; j < QPT; ++j) {
        const int q  = qbase + j * TPB;
        const int qc = (q < N) ? q : 0;  // clamped lanes duplicate pred 0: min-safe
        float4 t = Q[qc];
        p2x[j] = t.x; p2y[j] = t.y; p2z[j] = t.z; pw[j] = t.w;
        m[j] = 3.4e38f;
    }

#define PAIR(rr, jj) fmaf(p2x[jj], (rr).x, fmaf(p2y[jj], (rr).y, fmaf(p2z[jj], (rr).z, (rr).w)))

    unsigned* __restrict__ gdst = ugt + (size_t)b * M;

    int i = s0;
    if (s1 - s0 >= 8) {
        float4 r0 = R[i + 0], r1 = R[i + 1], r2 = R[i + 2], r3 = R[i + 3];
        for (; i + 8 <= s1; i += 4) {
            float4 n0 = R[i + 4], n1 = R[i + 5], n2 = R[i + 6], n3 = R[i + 7];
            float d0[QPT], d1[QPT], d2[QPT], d3[QPT];
            #pragma unroll
            for (int j = 0; j < QPT; ++j) {
                d0[j] = PAIR(r0, j);
                d1[j] = PAIR(r1, j);
                d2[j] = PAIR(r2, j);
                d3[j] = PAIR(r3, j);
                m[j] = fminf(fminf(m[j], d0[j]), d1[j]);  // -> v_min3_f32
                m[j] = fminf(fminf(m[j], d2[j]), d3[j]);
            }
            float t0 = gt_reduce(d0, pw);
            float t1 = gt_reduce(d1, pw);
            float t2 = gt_reduce(d2, pw);
            float t3 = gt_reduce(d3, pw);
            if ((lane & 15) == 0) {
                atomicMin(&gdst[i + 0], encf(t0));
                atomicMin(&gdst[i + 1], encf(t1));
                atomicMin(&gdst[i + 2], encf(t2));
                atomicMin(&gdst[i + 3], encf(t3));
            }
            r0 = n0; r1 = n1; r2 = n2; r3 = n3;
        }
        {
            float d0[QPT], d1[QPT], d2[QPT], d3[QPT];
            #pragma unroll
            for (int j = 0; j < QPT; ++j) {
                d0[j] = PAIR(r0, j);
                d1[j] = PAIR(r1, j);
                d2[j] = PAIR(r2, j);
                d3[j] = PAIR(r3, j);
                m[j] = fminf(fminf(m[j], d0[j]), d1[j]);
                m[j] = fminf(fminf(m[j], d2[j]), d3[j]);
            }
            float t0 = gt_reduce(d0, pw);
            float t1 = gt_reduce(d1, pw);
            float t2 = gt_reduce(d2, pw);
            float t3 = gt_reduce(d3, pw);
            if ((lane & 15) == 0) {
                atomicMin(&gdst[i + 0], encf(t0));
                atomicMin(&gdst[i + 1], encf(t1));
                atomicMin(&gdst[i + 2], encf(t2));
                atomicMin(&gdst[i + 3], encf(t3));
            }
            i += 4;
        }
    }
    for (; i < s1; ++i) {
        float4 r = R[i];
        float d[QPT];
        #pragma unroll
        for (int j = 0; j < QPT; ++j) {
            d[j] = PAIR(r, j);
            m[j] = fminf(m[j], d[j]);
        }
        float t = gt_reduce(d, pw);
        if ((lane & 15) == 0) atomicMin(&gdst[i], encf(t));
    }
#undef PAIR

    unsigned* __restrict__ pdst = upred + (size_t)b * N;
    #pragma unroll
    for (int j = 0; j < QPT; ++j) {
        const int q = qbase + j * TPB;
        if (q < N) atomicMin(&pdst[q], encf(m[j] + pw[j]));
    }
}

// One block per batch: decode + fixed-order sums for both directions.
__global__ void __launch_bounds__(256) finish(const unsigned* __restrict__ upred,
                                              const unsigned* __restrict__ ugt,
                                              float* __restrict__ out,
                                              int N, int M, int B) {
    const int b = blockIdx.x;
    const unsigned* m0 = upred + (size_t)b * N;
    const unsigned* m1 = ugt + (size_t)b * M;

    float s0 = 0.f, s1 = 0.f;
    for (int q = (int)threadIdx.x; q < N; q += 256) s0 += decf(m0[q]);
    for (int q = (int)threadIdx.x; q < M; q += 256) s1 += decf(m1[q]);

    for (int off = 32; off > 0; off >>= 1) {
        s0 += __shfl_down(s0, off);
        s1 += __shfl_down(s1, off);
    }
    __shared__ float r0s[4], r1s[4];
    const int wid  = (int)threadIdx.x >> 6;
    const int lane = (int)threadIdx.x & 63;
    if (lane == 0) { r0s[wid] = s0; r1s[wid] = s1; }
    __syncthreads();
    if (threadIdx.x == 0) {
        float S0 = 0.f, S1 = 0.f;
        #pragma unroll
        for (int w = 0; w < 4; ++w) { S0 += r0s[w]; S1 += r1s[w]; }
        out[b] = S0 / (float)N + S1 / (float)M;
    }
}

extern "C" void kernel_launch(void* const* d_in, const int* in_sizes, int n_in,
                              void* d_out, int out_size, void* d_ws, size_t ws_size,
                              hipStream_t stream) {
    const float* preds = (const float*)d_in[0];  // [B, N, 3]
    const float* gts   = (const float*)d_in[1];  // [B, M, 3]
    float* out = (float*)d_out;                  // [B]

    const int B = out_size;                      // 8
    const int N = in_sizes[0] / (B * 3);         // 8192
    const int M = in_sizes[1] / (B * 3);         // 8192

    float4*   P4    = (float4*)d_ws;             // [B*N]
    float4*   G4    = P4 + (size_t)B * N;        // [B*M]
    unsigned* upred = (unsigned*)(G4 + (size_t)B * M);  // [B*N]
    unsigned* ugt   = upred + (size_t)B * N;            // [B*M]

    const int totalP = B * N;
    const int totalG = B * M;
    const int totalU = B * (N + M);
    pack_preds<<<(totalP + 255) / 256, 256, 0, stream>>>(preds, P4, totalP);
    pack_gts<<<(totalG + 255) / 256, 256, 0, stream>>>(gts, G4, totalG);
    init_mins<<<(totalU + 255) / 256, 256, 0, stream>>>(upred, totalU);

    const int qChunks = (N + TPB * QPT - 1) / (TPB * QPT);
    dim3 grid(qChunks, NSEG, B);
    fused_chamfer<<<grid, TPB, 0, stream>>>(P4, G4, upred, ugt, N, M, B);

    finish<<<B, 256, 0, stream>>>(upred, ugt, out, N, M, B);
}